// Round 4
// baseline (903.108 us; speedup 1.0000x reference)
//
#include <hip/hip_runtime.h>
#include <stdint.h>

#define NLEV 16
#define LOG2T 19
#define TMASK ((1u << LOG2T) - 1u)
#define PRIME_Y 2654435761u
#define PRIME_Z 805459861u

typedef float f2v __attribute__((ext_vector_type(2)));
typedef float f4v __attribute__((ext_vector_type(4)));

// floor(16 * (2^0.4)^l) for l=0..15 (exact-math floors)
__constant__ float RESF_D[NLEV] = {16.f, 21.f, 27.f, 36.f, 48.f, 64.f, 84.f, 111.f,
                                   147.f, 194.f, 256.f, 337.f, 445.f, 588.f, 776.f, 1024.f};

// Encode one (point, level): 8 hashed gathers + trilinear blend.
__device__ __forceinline__ f2v enc_one(const float* __restrict__ x,
                                       const float2* __restrict__ tab,
                                       float res, int p)
{
    const float px = __builtin_nontemporal_load(x + 3 * p + 0);
    const float py = __builtin_nontemporal_load(x + 3 * p + 1);
    const float pz = __builtin_nontemporal_load(x + 3 * p + 2);
    const float fx = px * res, fy = py * res, fz = pz * res;
    const float gx = floorf(fx), gy = floorf(fy), gz = floorf(fz);
    const float wx = fx - gx, wy = fy - gy, wz = fz - gz;

    const uint32_t ux = (uint32_t)gx, uy = (uint32_t)gy, uz = (uint32_t)gz;
    const uint32_t hy0 = uy * PRIME_Y, hy1 = hy0 + PRIME_Y;
    const uint32_t hz0 = uz * PRIME_Z, hz1 = hz0 + PRIME_Z;
    const uint32_t x0 = ux, x1 = ux + 1u;

    const float2 c000 = tab[(x0 ^ hy0 ^ hz0) & TMASK];
    const float2 c001 = tab[(x0 ^ hy0 ^ hz1) & TMASK];
    const float2 c010 = tab[(x0 ^ hy1 ^ hz0) & TMASK];
    const float2 c011 = tab[(x0 ^ hy1 ^ hz1) & TMASK];
    const float2 c100 = tab[(x1 ^ hy0 ^ hz0) & TMASK];
    const float2 c101 = tab[(x1 ^ hy0 ^ hz1) & TMASK];
    const float2 c110 = tab[(x1 ^ hy1 ^ hz0) & TMASK];
    const float2 c111 = tab[(x1 ^ hy1 ^ hz1) & TMASK];

    const float ax = 1.f - wx, ay = 1.f - wy, az = 1.f - wz;
    const float w00 = ax * ay, w01 = ax * wy, w10 = wx * ay, w11 = wx * wy;
    const float w000 = w00 * az, w001 = w00 * wz;
    const float w010 = w01 * az, w011 = w01 * wz;
    const float w100 = w10 * az, w101 = w10 * wz;
    const float w110 = w11 * az, w111 = w11 * wz;

    f2v e;
    e.x = w000 * c000.x + w001 * c001.x + w010 * c010.x + w011 * c011.x +
          w100 * c100.x + w101 * c101.x + w110 * c110.x + w111 * c111.x;
    e.y = w000 * c000.y + w001 * c001.y + w010 * c010.y + w011 * c011.y +
          w100 * c100.y + w101 * c101.y + w110 * c110.y + w111 * c111.y;
    return e;
}

// ---------------------------------------------------------------------------
// E1: levels 6..13, one level per XCD (blockIdx%8), all N points, 2 pts/thread.
// enc layout: [level-6][N] f2v.
// ---------------------------------------------------------------------------
__global__ __launch_bounds__(256) void encode_mid_kernel(
    const float* __restrict__ x, const float* __restrict__ table,
    f2v* __restrict__ enc, int N)
{
    const int slot  = blockIdx.x & 7;
    const int chunk = blockIdx.x >> 3;
    const int level = 6 + slot;
    const float res = RESF_D[level];
    const float2* __restrict__ tab =
        reinterpret_cast<const float2*>(table) + ((size_t)level << LOG2T);
    f2v* __restrict__ encl = enc + (size_t)(level - 6) * N;

    const int p0 = chunk * 512 + threadIdx.x;
    const int p1 = p0 + 256;
    if (p0 >= N) return;
    const bool v1 = (p1 < N);
    const int p1c = v1 ? p1 : p0;

    const f2v e0 = enc_one(x, tab, res, p0);
    const f2v e1 = enc_one(x, tab, res, p1c);

    __builtin_nontemporal_store(e0, encl + p0);
    if (v1) __builtin_nontemporal_store(e1, encl + p1);
}

// ---------------------------------------------------------------------------
// E2: levels 14,15 split 4 XCDs each (point-quarters). slot = blockIdx%8:
//   level = 14 + (slot>>2), quarter = slot&3. 2 pts/thread.
// ---------------------------------------------------------------------------
__global__ __launch_bounds__(256) void encode_fine_kernel(
    const float* __restrict__ x, const float* __restrict__ table,
    f2v* __restrict__ enc, int N, int NQ, int bps)
{
    const int slot  = blockIdx.x & 7;
    const int chunk = blockIdx.x >> 3;
    const int level = 14 + (slot >> 2);
    const int q     = slot & 3;
    const float res = RESF_D[level];
    const float2* __restrict__ tab =
        reinterpret_cast<const float2*>(table) + ((size_t)level << LOG2T);
    f2v* __restrict__ encl = enc + (size_t)(level - 6) * N;

    const int local0 = chunk * 512 + threadIdx.x;
    const int base   = q * NQ;
    const int lim    = (q == 3) ? (N - base) : NQ;   // last quarter takes remainder
    if (local0 >= lim) return;
    const int local1 = local0 + 256;
    const bool v1 = (local1 < lim);
    const int p0 = base + local0;
    const int p1 = base + (v1 ? local1 : local0);

    const f2v e0 = enc_one(x, tab, res, p0);
    const f2v e1 = enc_one(x, tab, res, p1);

    __builtin_nontemporal_store(e0, encl + p0);
    if (v1) __builtin_nontemporal_store(e1, encl + p1);
}

// ---------------------------------------------------------------------------
// MLP + inline small levels 0..5 (tables 39KB..2.2MB: L1/L2-hot everywhere).
// 2 points per thread; weights via wave-uniform s_load, amortized over 2 pts.
// ---------------------------------------------------------------------------
__global__ __launch_bounds__(256) void mlp_small_kernel(
    const float* __restrict__ x, const float* __restrict__ table,
    const f2v* __restrict__ enc,
    const float* __restrict__ W1, const float* __restrict__ W2,
    float* __restrict__ out_sig, float* __restrict__ out_h, int N)
{
    const int p0 = blockIdx.x * 512 + threadIdx.x;
    if (p0 >= N) return;
    const int p1r = p0 + 256;
    const bool v1 = (p1r < N);
    const int p1 = v1 ? p1r : p0;

    float e0[32], e1[32];

    // small levels 0..5 inline
    constexpr float RESF_S[6] = {16.f, 21.f, 27.f, 36.f, 48.f, 64.f};
#pragma unroll
    for (int l = 0; l < 6; ++l) {
        const float2* __restrict__ tab =
            reinterpret_cast<const float2*>(table) + ((size_t)l << LOG2T);
        const f2v a = enc_one(x, tab, RESF_S[l], p0);
        const f2v b = enc_one(x, tab, RESF_S[l], p1);
        e0[2 * l + 0] = a.x; e0[2 * l + 1] = a.y;
        e1[2 * l + 0] = b.x; e1[2 * l + 1] = b.y;
    }
    // levels 6..15 from workspace
#pragma unroll
    for (int l = 6; l < 16; ++l) {
        const f2v* __restrict__ encl = enc + (size_t)(l - 6) * N;
        const f2v a = __builtin_nontemporal_load(encl + p0);
        const f2v b = __builtin_nontemporal_load(encl + p1);
        e0[2 * l + 0] = a.x; e0[2 * l + 1] = a.y;
        e1[2 * l + 0] = b.x; e1[2 * l + 1] = b.y;
    }

    float h0[16], h1[16];
#pragma unroll
    for (int o = 0; o < 16; ++o) { h0[o] = 0.f; h1[o] = 0.f; }

#pragma unroll
    for (int jt = 0; jt < 4; ++jt) {
        float a0[16], a1[16];
#pragma unroll
        for (int jj = 0; jj < 16; ++jj) { a0[jj] = 0.f; a1[jj] = 0.f; }
#pragma unroll
        for (int k = 0; k < 32; ++k) {
            const float* __restrict__ wrow = W1 + k * 64 + jt * 16;  // uniform -> s_load
            const float ek0 = e0[k], ek1 = e1[k];
#pragma unroll
            for (int jj = 0; jj < 16; ++jj) {
                const float w = wrow[jj];
                a0[jj] = fmaf(ek0, w, a0[jj]);
                a1[jj] = fmaf(ek1, w, a1[jj]);
            }
        }
#pragma unroll
        for (int jj = 0; jj < 16; ++jj) {
            const float r0 = fmaxf(a0[jj], 0.f);
            const float r1 = fmaxf(a1[jj], 0.f);
            const float* __restrict__ w2row = W2 + (jt * 16 + jj) * 16;  // uniform
#pragma unroll
            for (int o = 0; o < 16; ++o) {
                const float w = w2row[o];
                h0[o] = fmaf(r0, w, h0[o]);
                h1[o] = fmaf(r1, w, h1[o]);
            }
        }
    }

    __builtin_nontemporal_store(__expf(h0[0]), out_sig + p0);
    f4v* __restrict__ oh0 = reinterpret_cast<f4v*>(out_h + (size_t)p0 * 16);
#pragma unroll
    for (int qq = 0; qq < 4; ++qq) {
        f4v t = {h0[4 * qq + 0], h0[4 * qq + 1], h0[4 * qq + 2], h0[4 * qq + 3]};
        __builtin_nontemporal_store(t, oh0 + qq);
    }
    if (v1) {
        __builtin_nontemporal_store(__expf(h1[0]), out_sig + p1);
        f4v* __restrict__ oh1 = reinterpret_cast<f4v*>(out_h + (size_t)p1 * 16);
#pragma unroll
        for (int qq = 0; qq < 4; ++qq) {
            f4v t = {h1[4 * qq + 0], h1[4 * qq + 1], h1[4 * qq + 2], h1[4 * qq + 3]};
            __builtin_nontemporal_store(t, oh1 + qq);
        }
    }
}

// ---------------------------------------------------------------------------
// Fallback fused kernel (only if ws too small).
// ---------------------------------------------------------------------------
__global__ __launch_bounds__(256) void hashmlp_fused_kernel(
    const float* __restrict__ x, const float* __restrict__ table,
    const float* __restrict__ W1, const float* __restrict__ W2,
    float* __restrict__ out_sig, float* __restrict__ out_h, int N)
{
    const int i = blockIdx.x * 256 + threadIdx.x;
    if (i >= N) return;
    float e[32];
#pragma unroll
    for (int l = 0; l < NLEV; ++l) {
        const float2* __restrict__ tab =
            reinterpret_cast<const float2*>(table) + ((size_t)l << LOG2T);
        const f2v a = enc_one(x, tab, RESF_D[l], i);
        e[2 * l + 0] = a.x; e[2 * l + 1] = a.y;
    }
    float h[16];
#pragma unroll
    for (int o = 0; o < 16; ++o) h[o] = 0.f;
#pragma unroll
    for (int jt = 0; jt < 4; ++jt) {
        float acc[16];
#pragma unroll
        for (int jj = 0; jj < 16; ++jj) acc[jj] = 0.f;
#pragma unroll
        for (int k = 0; k < 32; ++k) {
            const float* __restrict__ wrow = W1 + k * 64 + jt * 16;
            const float ek = e[k];
#pragma unroll
            for (int jj = 0; jj < 16; ++jj) acc[jj] = fmaf(ek, wrow[jj], acc[jj]);
        }
#pragma unroll
        for (int jj = 0; jj < 16; ++jj) {
            const float a = fmaxf(acc[jj], 0.f);
            const float* __restrict__ w2row = W2 + (jt * 16 + jj) * 16;
#pragma unroll
            for (int o = 0; o < 16; ++o) h[o] = fmaf(a, w2row[o], h[o]);
        }
    }
    out_sig[i] = __expf(h[0]);
    float4* __restrict__ oh = reinterpret_cast<float4*>(out_h + (size_t)i * 16);
#pragma unroll
    for (int q = 0; q < 4; ++q)
        oh[q] = make_float4(h[4 * q + 0], h[4 * q + 1], h[4 * q + 2], h[4 * q + 3]);
}

extern "C" void kernel_launch(void* const* d_in, const int* in_sizes, int n_in,
                              void* d_out, int out_size, void* d_ws, size_t ws_size,
                              hipStream_t stream) {
    const float* x     = (const float*)d_in[0];
    const float* table = (const float*)d_in[1];
    const float* W1    = (const float*)d_in[2];
    const float* W2    = (const float*)d_in[3];

    const int N = in_sizes[0] / 3;
    float* out_sig = (float*)d_out;
    float* out_h   = (float*)d_out + N;

    const size_t enc_bytes = (size_t)10 * (size_t)N * sizeof(f2v);  // levels 6..15

    if (ws_size >= enc_bytes) {
        f2v* enc = (f2v*)d_ws;
        const int bps1 = (N + 511) / 512;           // blocks per slot, E1
        encode_mid_kernel<<<dim3(8 * bps1), 256, 0, stream>>>(x, table, enc, N);
        const int NQ   = N / 4;
        const int bps2 = (NQ + 511) / 512 + 1;      // +1 covers last-quarter remainder
        encode_fine_kernel<<<dim3(8 * bps2), 256, 0, stream>>>(x, table, enc, N, NQ, bps2);
        mlp_small_kernel<<<dim3(bps1), 256, 0, stream>>>(x, table, enc, W1, W2,
                                                         out_sig, out_h, N);
    } else {
        const int grid = (N + 255) / 256;
        hashmlp_fused_kernel<<<grid, 256, 0, stream>>>(x, table, W1, W2,
                                                       out_sig, out_h, N);
    }
}

// Round 5
// 579.292 us; speedup vs baseline: 1.5590x; 1.5590x over previous
//
#include <hip/hip_runtime.h>
#include <stdint.h>

#define NLEV 16
#define LOG2T 19
#define TMASK ((1u << LOG2T) - 1u)
#define PRIME_Y 2654435761u
#define PRIME_Z 805459861u

typedef float f2v __attribute__((ext_vector_type(2)));
typedef float f4v __attribute__((ext_vector_type(4)));
typedef short s4v __attribute__((ext_vector_type(4)));
typedef short s8v __attribute__((ext_vector_type(8)));

// floor(16 * (2^0.4)^l) for l=0..15
__constant__ float RESF_D[NLEV] = {16.f, 21.f, 27.f, 36.f, 48.f, 64.f, 84.f, 111.f,
                                   147.f, 194.f, 256.f, 337.f, 445.f, 588.f, 776.f, 1024.f};

static __device__ __forceinline__ unsigned short f2bf(float f) {
    return (unsigned short)(__float_as_uint(f) >> 16);   // truncate; values ~1e-4, threshold 2e-2
}

// Encode one (point, level) with x-corner pair-merge:
// PRIME_x == 1 -> idx(ux+1) == idx(ux)^1 when ux even; {idx, idx^1} is one aligned float4.
// Requests/point: 4 dwordx4 (+4 masked dwordx2 on odd-ux lanes) -> avg 6 vs 8.
__device__ __forceinline__ f2v enc_one(const float* __restrict__ x,
                                       const float2* __restrict__ tab,
                                       float res, int p)
{
    const float px = __builtin_nontemporal_load(x + 3 * p + 0);
    const float py = __builtin_nontemporal_load(x + 3 * p + 1);
    const float pz = __builtin_nontemporal_load(x + 3 * p + 2);
    const float fx = px * res, fy = py * res, fz = pz * res;
    const float gx = floorf(fx), gy = floorf(fy), gz = floorf(fz);
    const float wx = fx - gx, wy = fy - gy, wz = fz - gz;

    const uint32_t ux = (uint32_t)gx, uy = (uint32_t)gy, uz = (uint32_t)gz;
    const uint32_t hy0 = uy * PRIME_Y, hy1 = hy0 + PRIME_Y;
    const uint32_t hz0 = uz * PRIME_Z, hz1 = hz0 + PRIME_Z;
    const bool odd = (ux & 1u) != 0u;

    const uint32_t i00 = (ux ^ hy0 ^ hz0) & TMASK;
    const uint32_t i01 = (ux ^ hy0 ^ hz1) & TMASK;
    const uint32_t i10 = (ux ^ hy1 ^ hz0) & TMASK;
    const uint32_t i11 = (ux ^ hy1 ^ hz1) & TMASK;

    const f4v* __restrict__ tab4 = reinterpret_cast<const f4v*>(tab);
    const f4v q00 = tab4[i00 >> 1];
    const f4v q01 = tab4[i01 >> 1];
    const f4v q10 = tab4[i10 >> 1];
    const f4v q11 = tab4[i11 >> 1];

    f2v r00, r01, r10, r11;
    if (odd) {  // x1 corners not pair-adjacent: explicit loads (exec-masked, ~50% lanes)
        const uint32_t ux1 = ux + 1u;
        const f2v* __restrict__ tab2 = reinterpret_cast<const f2v*>(tab);
        r00 = tab2[(ux1 ^ hy0 ^ hz0) & TMASK];
        r01 = tab2[(ux1 ^ hy0 ^ hz1) & TMASK];
        r10 = tab2[(ux1 ^ hy1 ^ hz0) & TMASK];
        r11 = tab2[(ux1 ^ hy1 ^ hz1) & TMASK];
    }

    f2v c000, c001, c010, c011, c100, c101, c110, c111;
    {
        f2v lo, hi;
        lo.x = q00.x; lo.y = q00.y; hi.x = q00.z; hi.y = q00.w;
        c000 = (i00 & 1) ? hi : lo;  c100 = odd ? r00 : ((i00 & 1) ? lo : hi);
        lo.x = q01.x; lo.y = q01.y; hi.x = q01.z; hi.y = q01.w;
        c001 = (i01 & 1) ? hi : lo;  c101 = odd ? r01 : ((i01 & 1) ? lo : hi);
        lo.x = q10.x; lo.y = q10.y; hi.x = q10.z; hi.y = q10.w;
        c010 = (i10 & 1) ? hi : lo;  c110 = odd ? r10 : ((i10 & 1) ? lo : hi);
        lo.x = q11.x; lo.y = q11.y; hi.x = q11.z; hi.y = q11.w;
        c011 = (i11 & 1) ? hi : lo;  c111 = odd ? r11 : ((i11 & 1) ? lo : hi);
    }

    const float ax = 1.f - wx, ay = 1.f - wy, az = 1.f - wz;
    const float w00 = ax * ay, w01 = ax * wy, w10 = wx * ay, w11 = wx * wy;
    const float w000 = w00 * az, w001 = w00 * wz;
    const float w010 = w01 * az, w011 = w01 * wz;
    const float w100 = w10 * az, w101 = w10 * wz;
    const float w110 = w11 * az, w111 = w11 * wz;

    f2v e;
    e.x = w000 * c000.x + w001 * c001.x + w010 * c010.x + w011 * c011.x +
          w100 * c100.x + w101 * c101.x + w110 * c110.x + w111 * c111.x;
    e.y = w000 * c000.y + w001 * c001.y + w010 * c010.y + w011 * c011.y +
          w100 * c100.y + w101 * c101.y + w110 * c110.y + w111 * c111.y;
    return e;
}

static __device__ __forceinline__ void store_enc_bf16(unsigned* __restrict__ enc,
                                                      size_t idx, f2v e) {
    const unsigned packed = (unsigned)f2bf(e.x) | ((unsigned)f2bf(e.y) << 16);
    __builtin_nontemporal_store(packed, enc + idx);
}

// E1: levels 6..13, one level per XCD (blockIdx%8). enc: bf16x2 [level][N].
__global__ __launch_bounds__(256) void encode_mid_kernel(
    const float* __restrict__ x, const float* __restrict__ table,
    unsigned* __restrict__ enc, int N)
{
    const int slot  = blockIdx.x & 7;
    const int chunk = blockIdx.x >> 3;
    const int level = 6 + slot;
    const int p = chunk * 256 + threadIdx.x;
    if (p >= N) return;
    const float2* __restrict__ tab =
        reinterpret_cast<const float2*>(table) + ((size_t)level << LOG2T);
    const f2v e = enc_one(x, tab, RESF_D[level], p);
    store_enc_bf16(enc, (size_t)level * N + p, e);
}

// E2: levels 14,15, each split over 4 XCDs (point quarters).
__global__ __launch_bounds__(256) void encode_fine_kernel(
    const float* __restrict__ x, const float* __restrict__ table,
    unsigned* __restrict__ enc, int N, int NQ)
{
    const int slot  = blockIdx.x & 7;
    const int chunk = blockIdx.x >> 3;
    const int level = 14 + (slot >> 2);
    const int q     = slot & 3;
    const int base  = q * NQ;
    const int lim   = (q == 3) ? (N - base) : NQ;
    const int local = chunk * 256 + threadIdx.x;
    if (local >= lim) return;
    const int p = base + local;
    const float2* __restrict__ tab =
        reinterpret_cast<const float2*>(table) + ((size_t)level << LOG2T);
    const f2v e = enc_one(x, tab, RESF_D[level], p);
    store_enc_bf16(enc, (size_t)level * N + p, e);
}

// E3: levels 0..5 (tables total 3.8 MB -> co-resident in every XCD L2; L1 absorbs 0-2).
__global__ __launch_bounds__(256) void encode_small_kernel(
    const float* __restrict__ x, const float* __restrict__ table,
    unsigned* __restrict__ enc, int N)
{
    const int p = blockIdx.x * 256 + threadIdx.x;
    if (p >= N) return;
#pragma unroll
    for (int level = 0; level < 6; ++level) {
        const float2* __restrict__ tab =
            reinterpret_cast<const float2*>(table) + ((size_t)level << LOG2T);
        const f2v e = enc_one(x, tab, RESF_D[level], p);
        store_enc_bf16(enc, (size_t)level * N + p, e);
    }
}

// ---------------------------------------------------------------------------
// MFMA MLP. Swapped GEMMs so the point index rides the lane&15 (column) axis:
//   GEMM1: D1[hid][pt]  = mfma(A=W1^T tile, B=enc^T)   x4 hid-tiles, K=32
//   GEMM2: D2[out][pt]  = mfma(A=W2^T,      B=hid^T)   x2 K-chunks,  K=64
// Any intra-lane k-permutation cancels (same convention for A and B); C/D
// layout is the m89-verified col=lane&15, row=(lane>>4)*4+reg.
// hid^T bounced through padded LDS [16 pts][72 shorts] per wave (b64 w / b128 r).
// ---------------------------------------------------------------------------
__global__ __launch_bounds__(256) void mlp_mfma_kernel(
    const unsigned* __restrict__ enc,   // bf16x2 [16][N]
    const float* __restrict__ W1, const float* __restrict__ W2,
    float* __restrict__ out_sig, float* __restrict__ out_h, int N)
{
    __shared__ short hidT[4][16][72];

    const int lane = threadIdx.x & 63;
    const int w    = threadIdx.x >> 6;
    const int g    = lane >> 4;
    const int pt   = lane & 15;

    // One-time weight fragments (bf16).
    s8v a1[4], a2[2];
#pragma unroll
    for (int t = 0; t < 4; ++t)
#pragma unroll
        for (int j = 0; j < 8; ++j)
            a1[t][j] = (short)f2bf(W1[(8 * g + j) * 64 + 16 * t + pt]);
#pragma unroll
    for (int kc = 0; kc < 2; ++kc)
#pragma unroll
        for (int j = 0; j < 8; ++j)
            a2[kc][j] = (short)f2bf(W2[(32 * kc + 8 * g + j) * 16 + pt]);

    const f4v zero = {0.f, 0.f, 0.f, 0.f};
    const int base = (blockIdx.x * 4 + w) * 64;

#pragma unroll
    for (int it = 0; it < 4; ++it) {
        const int P0 = base + it * 16;

        // B1 frag: element j=2m+c  <-> feature 8g+2m+c = (level 4g+m, comp c).
        s8v b1;
#pragma unroll
        for (int m = 0; m < 4; ++m) {
            const unsigned v =
                __builtin_nontemporal_load(enc + (size_t)(4 * g + m) * N + P0 + pt);
            b1[2 * m + 0] = (short)(v & 0xffffu);
            b1[2 * m + 1] = (short)(v >> 16);
        }

        f4v c1[4];
#pragma unroll
        for (int t = 0; t < 4; ++t)
            c1[t] = __builtin_amdgcn_mfma_f32_16x16x32_bf16(a1[t], b1, zero, 0, 0, 0);

        __syncthreads();   // protect previous iteration's LDS reads
        // relu + bf16, write hid[pt][16t+4g..+3]
#pragma unroll
        for (int t = 0; t < 4; ++t) {
            s4v v;
#pragma unroll
            for (int r = 0; r < 4; ++r)
                v[r] = (short)f2bf(fmaxf(c1[t][r], 0.f));
            *reinterpret_cast<s4v*>(&hidT[w][pt][16 * t + 4 * g]) = v;
        }
        __syncthreads();

        f4v c2 = zero;
#pragma unroll
        for (int kc = 0; kc < 2; ++kc) {
            const s8v b2 =
                *reinterpret_cast<const s8v*>(&hidT[w][pt][32 * kc + 8 * g]);
            c2 = __builtin_amdgcn_mfma_f32_16x16x32_bf16(a2[kc], b2, c2, 0, 0, 0);
        }

        // D2[out=4g+r][pt]: 16B store at out_h[(P0+pt)*16 + 4g]
        f4v* __restrict__ oh =
            reinterpret_cast<f4v*>(out_h + ((size_t)(P0 + pt) * 16 + 4 * g));
        __builtin_nontemporal_store(c2, oh);
        if (g == 0) out_sig[P0 + pt] = __expf(c2[0]);
    }
}

// Fallback fused kernel (ws too small or N not a multiple of 256).
__global__ __launch_bounds__(256) void hashmlp_fused_kernel(
    const float* __restrict__ x, const float* __restrict__ table,
    const float* __restrict__ W1, const float* __restrict__ W2,
    float* __restrict__ out_sig, float* __restrict__ out_h, int N)
{
    const int i = blockIdx.x * 256 + threadIdx.x;
    if (i >= N) return;
    float e[32];
#pragma unroll
    for (int l = 0; l < NLEV; ++l) {
        const float2* __restrict__ tab =
            reinterpret_cast<const float2*>(table) + ((size_t)l << LOG2T);
        const f2v a = enc_one(x, tab, RESF_D[l], i);
        e[2 * l + 0] = a.x; e[2 * l + 1] = a.y;
    }
    float h[16];
#pragma unroll
    for (int o = 0; o < 16; ++o) h[o] = 0.f;
#pragma unroll
    for (int jt = 0; jt < 4; ++jt) {
        float acc[16];
#pragma unroll
        for (int jj = 0; jj < 16; ++jj) acc[jj] = 0.f;
#pragma unroll
        for (int k = 0; k < 32; ++k) {
            const float* __restrict__ wrow = W1 + k * 64 + jt * 16;
            const float ek = e[k];
#pragma unroll
            for (int jj = 0; jj < 16; ++jj) acc[jj] = fmaf(ek, wrow[jj], acc[jj]);
        }
#pragma unroll
        for (int jj = 0; jj < 16; ++jj) {
            const float a = fmaxf(acc[jj], 0.f);
            const float* __restrict__ w2row = W2 + (jt * 16 + jj) * 16;
#pragma unroll
            for (int o = 0; o < 16; ++o) h[o] = fmaf(a, w2row[o], h[o]);
        }
    }
    out_sig[i] = __expf(h[0]);
    float4* __restrict__ oh = reinterpret_cast<float4*>(out_h + (size_t)i * 16);
#pragma unroll
    for (int q = 0; q < 4; ++q)
        oh[q] = make_float4(h[4 * q + 0], h[4 * q + 1], h[4 * q + 2], h[4 * q + 3]);
}

extern "C" void kernel_launch(void* const* d_in, const int* in_sizes, int n_in,
                              void* d_out, int out_size, void* d_ws, size_t ws_size,
                              hipStream_t stream) {
    const float* x     = (const float*)d_in[0];
    const float* table = (const float*)d_in[1];
    const float* W1    = (const float*)d_in[2];
    const float* W2    = (const float*)d_in[3];

    const int N = in_sizes[0] / 3;
    float* out_sig = (float*)d_out;
    float* out_h   = (float*)d_out + N;

    const size_t enc_bytes = (size_t)NLEV * (size_t)N * sizeof(unsigned);  // bf16x2

    if (ws_size >= enc_bytes && (N % 256) == 0) {
        unsigned* enc = (unsigned*)d_ws;
        const int chunks = N / 256;
        encode_mid_kernel<<<dim3(8 * chunks), 256, 0, stream>>>(x, table, enc, N);
        const int NQ   = N / 4;
        const int rem  = N - 3 * NQ;
        const int bps2 = (rem + 255) / 256;
        encode_fine_kernel<<<dim3(8 * bps2), 256, 0, stream>>>(x, table, enc, N, NQ);
        encode_small_kernel<<<dim3(chunks), 256, 0, stream>>>(x, table, enc, N);
        mlp_mfma_kernel<<<dim3(chunks), 256, 0, stream>>>(enc, W1, W2,
                                                          out_sig, out_h, N);
    } else {
        const int grid = (N + 255) / 256;
        hashmlp_fused_kernel<<<grid, 256, 0, stream>>>(x, table, W1, W2,
                                                       out_sig, out_h, N);
    }
}

// Round 7
// 563.528 us; speedup vs baseline: 1.6026x; 1.0280x over previous
//
#include <hip/hip_runtime.h>
#include <stdint.h>

#define NLEV 16
#define LOG2T 19
#define TMASK ((1u << LOG2T) - 1u)
#define PRIME_Y 2654435761u
#define PRIME_Z 805459861u
#define GRES 64
#define NCELLS (GRES * GRES * GRES)   // 262144 Morton buckets

typedef float f2v __attribute__((ext_vector_type(2)));
typedef float f4v __attribute__((ext_vector_type(4)));
typedef short s4v __attribute__((ext_vector_type(4)));
typedef short s8v __attribute__((ext_vector_type(8)));

// floor(16 * (2^0.4)^l) for l=0..15
__constant__ float RESF_D[NLEV] = {16.f, 21.f, 27.f, 36.f, 48.f, 64.f, 84.f, 111.f,
                                   147.f, 194.f, 256.f, 337.f, 445.f, 588.f, 776.f, 1024.f};

static __device__ __forceinline__ unsigned short f2bf(float f) {
    return (unsigned short)(__float_as_uint(f) >> 16);
}

static __device__ __forceinline__ uint32_t spread3(uint32_t v) {
    v = (v | (v << 16)) & 0x030000FFu;
    v = (v | (v << 8))  & 0x0300F00Fu;
    v = (v | (v << 4))  & 0x030C30C3u;
    v = (v | (v << 2))  & 0x09249249u;
    return v;
}

static __device__ __forceinline__ uint32_t cell_of(float px, float py, float pz) {
    const uint32_t cx = min((uint32_t)(px * (float)GRES), (uint32_t)(GRES - 1));
    const uint32_t cy = min((uint32_t)(py * (float)GRES), (uint32_t)(GRES - 1));
    const uint32_t cz = min((uint32_t)(pz * (float)GRES), (uint32_t)(GRES - 1));
    return spread3(cx) | (spread3(cy) << 1) | (spread3(cz) << 2);
}

// Encode one (point, level) with x-corner pair-merge (PRIME_x == 1).
__device__ __forceinline__ f2v enc_one(float px, float py, float pz,
                                       const float2* __restrict__ tab, float res)
{
    const float fx = px * res, fy = py * res, fz = pz * res;
    const float gx = floorf(fx), gy = floorf(fy), gz = floorf(fz);
    const float wx = fx - gx, wy = fy - gy, wz = fz - gz;

    const uint32_t ux = (uint32_t)gx, uy = (uint32_t)gy, uz = (uint32_t)gz;
    const uint32_t hy0 = uy * PRIME_Y, hy1 = hy0 + PRIME_Y;
    const uint32_t hz0 = uz * PRIME_Z, hz1 = hz0 + PRIME_Z;
    const bool odd = (ux & 1u) != 0u;

    const uint32_t i00 = (ux ^ hy0 ^ hz0) & TMASK;
    const uint32_t i01 = (ux ^ hy0 ^ hz1) & TMASK;
    const uint32_t i10 = (ux ^ hy1 ^ hz0) & TMASK;
    const uint32_t i11 = (ux ^ hy1 ^ hz1) & TMASK;

    const f4v* __restrict__ tab4 = reinterpret_cast<const f4v*>(tab);
    const f4v q00 = tab4[i00 >> 1];
    const f4v q01 = tab4[i01 >> 1];
    const f4v q10 = tab4[i10 >> 1];
    const f4v q11 = tab4[i11 >> 1];

    f2v r00, r01, r10, r11;
    if (odd) {
        const uint32_t ux1 = ux + 1u;
        const f2v* __restrict__ tab2 = reinterpret_cast<const f2v*>(tab);
        r00 = tab2[(ux1 ^ hy0 ^ hz0) & TMASK];
        r01 = tab2[(ux1 ^ hy0 ^ hz1) & TMASK];
        r10 = tab2[(ux1 ^ hy1 ^ hz0) & TMASK];
        r11 = tab2[(ux1 ^ hy1 ^ hz1) & TMASK];
    }

    f2v c000, c001, c010, c011, c100, c101, c110, c111;
    {
        f2v lo, hi;
        lo.x = q00.x; lo.y = q00.y; hi.x = q00.z; hi.y = q00.w;
        c000 = (i00 & 1) ? hi : lo;  c100 = odd ? r00 : ((i00 & 1) ? lo : hi);
        lo.x = q01.x; lo.y = q01.y; hi.x = q01.z; hi.y = q01.w;
        c001 = (i01 & 1) ? hi : lo;  c101 = odd ? r01 : ((i01 & 1) ? lo : hi);
        lo.x = q10.x; lo.y = q10.y; hi.x = q10.z; hi.y = q10.w;
        c010 = (i10 & 1) ? hi : lo;  c110 = odd ? r10 : ((i10 & 1) ? lo : hi);
        lo.x = q11.x; lo.y = q11.y; hi.x = q11.z; hi.y = q11.w;
        c011 = (i11 & 1) ? hi : lo;  c111 = odd ? r11 : ((i11 & 1) ? lo : hi);
    }

    const float ax = 1.f - wx, ay = 1.f - wy, az = 1.f - wz;
    const float w00 = ax * ay, w01 = ax * wy, w10 = wx * ay, w11 = wx * wy;
    const float w000 = w00 * az, w001 = w00 * wz;
    const float w010 = w01 * az, w011 = w01 * wz;
    const float w100 = w10 * az, w101 = w10 * wz;
    const float w110 = w11 * az, w111 = w11 * wz;

    f2v e;
    e.x = w000 * c000.x + w001 * c001.x + w010 * c010.x + w011 * c011.x +
          w100 * c100.x + w101 * c101.x + w110 * c110.x + w111 * c111.x;
    e.y = w000 * c000.y + w001 * c001.y + w010 * c010.y + w011 * c011.y +
          w100 * c100.y + w101 * c101.y + w110 * c110.y + w111 * c111.y;
    return e;
}

static __device__ __forceinline__ void store_enc_bf16(unsigned* __restrict__ enc,
                                                      size_t idx, f2v e) {
    const unsigned packed = (unsigned)f2bf(e.x) | ((unsigned)f2bf(e.y) << 16);
    __builtin_nontemporal_store(packed, enc + idx);
}

// ---- sort pipeline ---------------------------------------------------------
__global__ __launch_bounds__(256) void hist_kernel(
    const float* __restrict__ x, uint32_t* __restrict__ hist, int N)
{
    const int i = blockIdx.x * 256 + threadIdx.x;
    if (i >= N) return;
    const uint32_t c = cell_of(x[3 * i], x[3 * i + 1], x[3 * i + 2]);
    atomicAdd(&hist[c], 1u);
}

__global__ __launch_bounds__(1024) void scan_block_kernel(
    uint32_t* __restrict__ hist, uint32_t* __restrict__ bsum)
{
    __shared__ uint32_t sa[1024], sb[1024];
    const int t = threadIdx.x;
    const uint32_t orig = hist[blockIdx.x * 1024 + t];
    sa[t] = orig;
    __syncthreads();
    uint32_t* src = sa;
    uint32_t* dst = sb;
    for (int off = 1; off < 1024; off <<= 1) {
        dst[t] = (t >= off) ? (src[t] + src[t - off]) : src[t];
        __syncthreads();
        uint32_t* tmp = src; src = dst; dst = tmp;
    }
    hist[blockIdx.x * 1024 + t] = src[t] - orig;          // exclusive within block
    if (t == 1023) bsum[blockIdx.x] = src[1023];          // block total
}

__global__ __launch_bounds__(256) void scan_tops_kernel(uint32_t* __restrict__ bsum)
{
    __shared__ uint32_t sa[256], sb[256];
    const int t = threadIdx.x;
    const uint32_t orig = bsum[t];
    sa[t] = orig;
    __syncthreads();
    uint32_t* src = sa;
    uint32_t* dst = sb;
    for (int off = 1; off < 256; off <<= 1) {
        dst[t] = (t >= off) ? (src[t] + src[t - off]) : src[t];
        __syncthreads();
        uint32_t* tmp = src; src = dst; dst = tmp;
    }
    bsum[t] = src[t] - orig;                              // exclusive
}

__global__ __launch_bounds__(256) void scatter_kernel(
    const float* __restrict__ x, uint32_t* __restrict__ hist,
    const uint32_t* __restrict__ bsum,
    float* __restrict__ xs, uint32_t* __restrict__ oidx, int N)
{
    const int i = blockIdx.x * 256 + threadIdx.x;
    if (i >= N) return;
    const float px = x[3 * i], py = x[3 * i + 1], pz = x[3 * i + 2];
    const uint32_t c = cell_of(px, py, pz);
    const uint32_t r = atomicAdd(&hist[c], 1u);           // pre-add = excl-in-block + rank
    const uint32_t pos = bsum[c >> 10] + r;
    xs[3 * pos + 0] = px;
    xs[3 * pos + 1] = py;
    xs[3 * pos + 2] = pz;
    oidx[pos] = (uint32_t)i;
}

// ---- encode (sorted domain) ------------------------------------------------
// Fine levels 8..15: one level per XCD (blockIdx%8), request-balanced (~6M each).
__global__ __launch_bounds__(256) void encode_fine_kernel(
    const float* __restrict__ xs, const float* __restrict__ table,
    unsigned* __restrict__ enc, int N)
{
    const int slot  = blockIdx.x & 7;
    const int chunk = blockIdx.x >> 3;
    const int level = 8 + slot;
    const int p = chunk * 256 + threadIdx.x;
    if (p >= N) return;
    const float px = __builtin_nontemporal_load(xs + 3 * p + 0);
    const float py = __builtin_nontemporal_load(xs + 3 * p + 1);
    const float pz = __builtin_nontemporal_load(xs + 3 * p + 2);
    const float2* __restrict__ tab =
        reinterpret_cast<const float2*>(table) + ((size_t)level << LOG2T);
    const f2v e = enc_one(px, py, pz, tab, RESF_D[level]);
    store_enc_bf16(enc, (size_t)level * N + p, e);
}

// Coarse levels 0..7: sorted waves share corners -> same-address lanes merge
// into single L2 requests. All XCDs, all levels per block.
__global__ __launch_bounds__(256) void encode_coarse_kernel(
    const float* __restrict__ xs, const float* __restrict__ table,
    unsigned* __restrict__ enc, int N)
{
    const int p = blockIdx.x * 256 + threadIdx.x;
    if (p >= N) return;
    const float px = __builtin_nontemporal_load(xs + 3 * p + 0);
    const float py = __builtin_nontemporal_load(xs + 3 * p + 1);
    const float pz = __builtin_nontemporal_load(xs + 3 * p + 2);
#pragma unroll 2
    for (int level = 0; level < 8; ++level) {
        const float2* __restrict__ tab =
            reinterpret_cast<const float2*>(table) + ((size_t)level << LOG2T);
        const f2v e = enc_one(px, py, pz, tab, RESF_D[level]);
        store_enc_bf16(enc, (size_t)level * N + p, e);
    }
}

// ---- MFMA MLP (sorted domain, scatter on output) ---------------------------
__global__ __launch_bounds__(256) void mlp_mfma_kernel(
    const unsigned* __restrict__ enc,   // bf16x2 [16][N] (sorted)
    const uint32_t* __restrict__ oidx,  // sorted -> original
    const float* __restrict__ W1, const float* __restrict__ W2,
    float* __restrict__ out_sig, float* __restrict__ out_h, int N)
{
    __shared__ short hidT[4][16][72];

    const int lane = threadIdx.x & 63;
    const int w    = threadIdx.x >> 6;
    const int g    = lane >> 4;
    const int pt   = lane & 15;

    s8v a1[4], a2[2];
#pragma unroll
    for (int t = 0; t < 4; ++t)
#pragma unroll
        for (int j = 0; j < 8; ++j)
            a1[t][j] = (short)f2bf(W1[(8 * g + j) * 64 + 16 * t + pt]);
#pragma unroll
    for (int kc = 0; kc < 2; ++kc)
#pragma unroll
        for (int j = 0; j < 8; ++j)
            a2[kc][j] = (short)f2bf(W2[(32 * kc + 8 * g + j) * 16 + pt]);

    const f4v zero = {0.f, 0.f, 0.f, 0.f};
    const int base = (blockIdx.x * 4 + w) * 64;

#pragma unroll
    for (int it = 0; it < 4; ++it) {
        const int P0 = base + it * 16;
        const int orig = (int)oidx[P0 + pt];

        s8v b1;
#pragma unroll
        for (int m = 0; m < 4; ++m) {
            const unsigned v =
                __builtin_nontemporal_load(enc + (size_t)(4 * g + m) * N + P0 + pt);
            b1[2 * m + 0] = (short)(v & 0xffffu);
            b1[2 * m + 1] = (short)(v >> 16);
        }

        f4v c1[4];
#pragma unroll
        for (int t = 0; t < 4; ++t)
            c1[t] = __builtin_amdgcn_mfma_f32_16x16x32_bf16(a1[t], b1, zero, 0, 0, 0);

        __syncthreads();
#pragma unroll
        for (int t = 0; t < 4; ++t) {
            s4v v;
#pragma unroll
            for (int r = 0; r < 4; ++r)
                v[r] = (short)f2bf(fmaxf(c1[t][r], 0.f));
            *reinterpret_cast<s4v*>(&hidT[w][pt][16 * t + 4 * g]) = v;
        }
        __syncthreads();

        f4v c2 = zero;
#pragma unroll
        for (int kc = 0; kc < 2; ++kc) {
            const s8v b2 =
                *reinterpret_cast<const s8v*>(&hidT[w][pt][32 * kc + 8 * g]);
            c2 = __builtin_amdgcn_mfma_f32_16x16x32_bf16(a2[kc], b2, c2, 0, 0, 0);
        }

        f4v* __restrict__ oh =
            reinterpret_cast<f4v*>(out_h + ((size_t)orig * 16 + 4 * g));
        __builtin_nontemporal_store(c2, oh);
        if (g == 0) out_sig[orig] = __expf(c2[0]);
    }
}

// ---- fallback fused (safety only) ------------------------------------------
__global__ __launch_bounds__(256) void hashmlp_fused_kernel(
    const float* __restrict__ x, const float* __restrict__ table,
    const float* __restrict__ W1, const float* __restrict__ W2,
    float* __restrict__ out_sig, float* __restrict__ out_h, int N)
{
    const int i = blockIdx.x * 256 + threadIdx.x;
    if (i >= N) return;
    const float px = x[3 * i], py = x[3 * i + 1], pz = x[3 * i + 2];
    float e[32];
#pragma unroll
    for (int l = 0; l < NLEV; ++l) {
        const float2* __restrict__ tab =
            reinterpret_cast<const float2*>(table) + ((size_t)l << LOG2T);
        const f2v a = enc_one(px, py, pz, tab, RESF_D[l]);
        e[2 * l + 0] = a.x; e[2 * l + 1] = a.y;
    }
    float h[16];
#pragma unroll
    for (int o = 0; o < 16; ++o) h[o] = 0.f;
#pragma unroll
    for (int jt = 0; jt < 4; ++jt) {
        float acc[16];
#pragma unroll
        for (int jj = 0; jj < 16; ++jj) acc[jj] = 0.f;
#pragma unroll
        for (int k = 0; k < 32; ++k) {
            const float* __restrict__ wrow = W1 + k * 64 + jt * 16;
            const float ek = e[k];
#pragma unroll
            for (int jj = 0; jj < 16; ++jj) acc[jj] = fmaf(ek, wrow[jj], acc[jj]);
        }
#pragma unroll
        for (int jj = 0; jj < 16; ++jj) {
            const float a = fmaxf(acc[jj], 0.f);
            const float* __restrict__ w2row = W2 + (jt * 16 + jj) * 16;
#pragma unroll
            for (int o = 0; o < 16; ++o) h[o] = fmaf(a, w2row[o], h[o]);
        }
    }
    out_sig[i] = __expf(h[0]);
    float4* __restrict__ oh = reinterpret_cast<float4*>(out_h + (size_t)i * 16);
#pragma unroll
    for (int q = 0; q < 4; ++q)
        oh[q] = make_float4(h[4 * q + 0], h[4 * q + 1], h[4 * q + 2], h[4 * q + 3]);
}

extern "C" void kernel_launch(void* const* d_in, const int* in_sizes, int n_in,
                              void* d_out, int out_size, void* d_ws, size_t ws_size,
                              hipStream_t stream) {
    const float* x     = (const float*)d_in[0];
    const float* table = (const float*)d_in[1];
    const float* W1    = (const float*)d_in[2];
    const float* W2    = (const float*)d_in[3];

    const int N = in_sizes[0] / 3;
    float* out_sig = (float*)d_out;
    float* out_h   = (float*)d_out + N;

    // ws layout: enc 64MB | xs 12MB | oidx 4MB | hist 1MB | bsum 1KB
    uint8_t* ws = (uint8_t*)d_ws;
    const size_t enc_off  = 0;
    const size_t xs_off   = (size_t)NLEV * N * 4;                 // 64MB @ N=2^20
    const size_t oidx_off = xs_off + (size_t)N * 3 * 4;           // +12MB
    const size_t hist_off = oidx_off + (size_t)N * 4;             // +4MB
    const size_t bsum_off = hist_off + (size_t)NCELLS * 4;        // +1MB
    const size_t need     = bsum_off + 256 * 4;

    if (ws_size >= need && (N % 1024) == 0) {
        unsigned* enc   = (unsigned*)(ws + enc_off);
        float*    xs    = (float*)(ws + xs_off);
        uint32_t* oidx  = (uint32_t*)(ws + oidx_off);
        uint32_t* hist  = (uint32_t*)(ws + hist_off);
        uint32_t* bsum  = (uint32_t*)(ws + bsum_off);

        const int chunks = N / 256;
        hipMemsetAsync(hist, 0, (size_t)NCELLS * 4 + 256 * 4, stream);
        hist_kernel<<<dim3(chunks), 256, 0, stream>>>(x, hist, N);
        scan_block_kernel<<<dim3(NCELLS / 1024), 1024, 0, stream>>>(hist, bsum);
        scan_tops_kernel<<<dim3(1), 256, 0, stream>>>(bsum);
        scatter_kernel<<<dim3(chunks), 256, 0, stream>>>(x, hist, bsum, xs, oidx, N);

        encode_fine_kernel<<<dim3(8 * chunks), 256, 0, stream>>>(xs, table, enc, N);
        encode_coarse_kernel<<<dim3(chunks), 256, 0, stream>>>(xs, table, enc, N);
        mlp_mfma_kernel<<<dim3(chunks), 256, 0, stream>>>(enc, oidx, W1, W2,
                                                          out_sig, out_h, N);
    } else {
        const int grid = (N + 255) / 256;
        hashmlp_fused_kernel<<<grid, 256, 0, stream>>>(x, table, W1, W2,
                                                       out_sig, out_h, N);
    }
}